// Round 7
// baseline (452.003 us; speedup 1.0000x reference)
//
#include <hip/hip_runtime.h>
#include <hip/hip_bf16.h>

// Haar wavelet transform: x (16,64,512,512) f32 -> 4 planes (16,64,256,256) f32.
//
// R7: bank-level skew of the 4 plane write streams.
// Theory: planes are 256MB apart; concurrent writes to the same within-plane
// offset hit the SAME DRAM bank with 4 different rows -> activate storms.
// R6's 1-3KB row rotation only decorrelated channels (+2%). Here each block
// stages FOUR tiles that are 2048 tiles (32MB) apart in LDS; in the write
// phase wave w writes plane w for the 4 tiles in rotated order, so concurrent
// plane streams sit at within-plane offsets >=32MB apart (different banks AND
// rows). Also: deep same-direction bursts (16x1KB loads then 16x1KB stores
// per wave) and 4x fewer barriers.
//
// tiles: 65536 total (1024 channels x 64 row-groups). 8 super-iters;
// per super-iter block b handles tiles {s*8192 + k*2048 + b, k=0..3}.

#define B_ 16
#define C_ 64
#define H_ 512
#define W_ 512
#define HO (H_/2)
#define WO (W_/2)
#define NPLANE (B_*C_*HO*WO)     // 67,108,864 elements per plane

typedef float f32x4 __attribute__((ext_vector_type(4)));
typedef float f32x2 __attribute__((ext_vector_type(2)));

__global__ __launch_bounds__(256) void haar_kernel(const float* __restrict__ x,
                                                   float* __restrict__ out) {
    __shared__ float lds[4][4][4][256];   // [tile][row_in_tile][plane][col] = 64KB
    const int w    = threadIdx.x >> 6;    // wave 0..3
    const int lane = threadIdx.x & 63;

    for (int s = 0; s < 8; ++s) {
        // ---- Phase A: compute 4 tiles (each 32MB apart) into LDS ----
#pragma unroll
        for (int k = 0; k < 4; ++k) {
            const int t  = s * 8192 + k * 2048 + (int)blockIdx.x;
            const int bc = t >> 6;        // channel 0..1023
            const int h4 = t & 63;        // row-group 0..63

            const float* in_row = x + (size_t)bc * (H_ * W_)
                                    + (size_t)(h4 * 8 + 2 * w) * W_ + 4 * lane;
            const f32x4 r0a = *reinterpret_cast<const f32x4*>(in_row);
            const f32x4 r0b = *reinterpret_cast<const f32x4*>(in_row + 256);
            const f32x4 r1a = *reinterpret_cast<const f32x4*>(in_row + W_);
            const f32x4 r1b = *reinterpret_cast<const f32x4*>(in_row + W_ + 256);

            f32x2 ll_a, lh_a, hl_a, hh_a, ll_b, lh_b, hl_b, hh_b;
            {
                float p0 = r0a[0] + r0a[1], q0 = r0a[0] - r0a[1];
                float r0 = r1a[0] + r1a[1], s0 = r1a[0] - r1a[1];
                ll_a[0] = (p0 + r0) * 0.5f; hl_a[0] = (p0 - r0) * 0.5f;
                lh_a[0] = (q0 + s0) * 0.5f; hh_a[0] = (q0 - s0) * 0.5f;
                float p1 = r0a[2] + r0a[3], q1 = r0a[2] - r0a[3];
                float r1 = r1a[2] + r1a[3], s1 = r1a[2] - r1a[3];
                ll_a[1] = (p1 + r1) * 0.5f; hl_a[1] = (p1 - r1) * 0.5f;
                lh_a[1] = (q1 + s1) * 0.5f; hh_a[1] = (q1 - s1) * 0.5f;
            }
            {
                float p0 = r0b[0] + r0b[1], q0 = r0b[0] - r0b[1];
                float r0 = r1b[0] + r1b[1], s0 = r1b[0] - r1b[1];
                ll_b[0] = (p0 + r0) * 0.5f; hl_b[0] = (p0 - r0) * 0.5f;
                lh_b[0] = (q0 + s0) * 0.5f; hh_b[0] = (q0 - s0) * 0.5f;
                float p1 = r0b[2] + r0b[3], q1 = r0b[2] - r0b[3];
                float r1 = r1b[2] + r1b[3], s1 = r1b[2] - r1b[3];
                ll_b[1] = (p1 + r1) * 0.5f; hl_b[1] = (p1 - r1) * 0.5f;
                lh_b[1] = (q1 + s1) * 0.5f; hh_b[1] = (q1 - s1) * 0.5f;
            }

            *reinterpret_cast<f32x2*>(&lds[k][w][0][2 * lane])       = ll_a;
            *reinterpret_cast<f32x2*>(&lds[k][w][0][128 + 2 * lane]) = ll_b;
            *reinterpret_cast<f32x2*>(&lds[k][w][1][2 * lane])       = lh_a;
            *reinterpret_cast<f32x2*>(&lds[k][w][1][128 + 2 * lane]) = lh_b;
            *reinterpret_cast<f32x2*>(&lds[k][w][2][2 * lane])       = hl_a;
            *reinterpret_cast<f32x2*>(&lds[k][w][2][128 + 2 * lane]) = hl_b;
            *reinterpret_cast<f32x2*>(&lds[k][w][3][2 * lane])       = hh_a;
            *reinterpret_cast<f32x2*>(&lds[k][w][3][128 + 2 * lane]) = hh_b;
        }

        __syncthreads();

        // ---- Phase B: wave w writes plane w for the 4 tiles, rotated ----
#pragma unroll
        for (int k = 0; k < 4; ++k) {
            const int kk = (w + k) & 3;
            const int t  = s * 8192 + kk * 2048 + (int)blockIdx.x;
            const int bc = t >> 6;
            const int h4 = t & 63;

            float* pb = out + (size_t)w * NPLANE + (size_t)bc * (HO * WO)
                            + (size_t)(h4 * 4) * WO + 4 * lane;
#pragma unroll
            for (int r = 0; r < 4; ++r) {
                const f32x4 v = *reinterpret_cast<const f32x4*>(&lds[kk][r][w][4 * lane]);
                *reinterpret_cast<f32x4*>(pb + (size_t)r * WO) = v;
            }
        }

        __syncthreads();   // LDS reused next super-iteration
    }
}

extern "C" void kernel_launch(void* const* d_in, const int* in_sizes, int n_in,
                              void* d_out, int out_size, void* d_ws, size_t ws_size,
                              hipStream_t stream) {
    const float* x = (const float*)d_in[0];
    float* out = (float*)d_out;
    haar_kernel<<<2048, 256, 0, stream>>>(x, out);
}

// Round 8
// 396.284 us; speedup vs baseline: 1.1406x; 1.1406x over previous
//
#include <hip/hip_runtime.h>
#include <hip/hip_bf16.h>

// Haar wavelet transform: x (16,64,512,512) f32 -> 4 planes (16,64,256,256) f32.
//
// R8: R6 structure (best: 421us) minus the block loop — one tile per block,
// 65536 blocks, single barrier, no phase-synchronized load/store pulsing.
// Theory: R6's 32 barrier-separated iterations keep all waves (and roughly
// all blocks) alternating read-burst/write-burst in lockstep; one-shot
// blocks retire and are replaced continuously, smoothing the read/write mix
// at the memory controllers.
//
// Tile = 4 output rows x 256 cols x 4 planes (one channel row-group).
// Phase A: wave w computes input row pair (2w, 2w+1) -> LDS (4KB contiguous
//          read per wave). Phase B: wave w writes plane w, 4 rows rotated
//          (4KB contiguous write per wave).

#define B_ 16
#define C_ 64
#define H_ 512
#define W_ 512
#define HO (H_/2)
#define WO (W_/2)
#define NPLANE (B_*C_*HO*WO)     // 67,108,864 elements per plane

typedef float f32x4 __attribute__((ext_vector_type(4)));
typedef float f32x2 __attribute__((ext_vector_type(2)));

__global__ __launch_bounds__(256) void haar_kernel(const float* __restrict__ x,
                                                   float* __restrict__ out) {
    __shared__ float lds[4][4][256];     // [out_row_in_tile][plane][col] = 16KB
    const int w    = threadIdx.x >> 6;   // wave id 0..3
    const int lane = threadIdx.x & 63;

    const int t  = (int)blockIdx.x;      // tile id 0..65535
    const int bc = t >> 6;               // channel 0..1023
    const int h4 = t & 63;               // row group 0..63

    // ---- Phase A: dense 4KB-contiguous load per wave + butterfly -> LDS ----
    const float* in_row = x + (size_t)bc * (H_ * W_)
                            + (size_t)(h4 * 8 + 2 * w) * W_ + 4 * lane;
    const f32x4 r0a = *reinterpret_cast<const f32x4*>(in_row);
    const f32x4 r0b = *reinterpret_cast<const f32x4*>(in_row + 256);
    const f32x4 r1a = *reinterpret_cast<const f32x4*>(in_row + W_);
    const f32x4 r1b = *reinterpret_cast<const f32x4*>(in_row + W_ + 256);

    f32x2 ll_a, lh_a, hl_a, hh_a, ll_b, lh_b, hl_b, hh_b;
    {
        float p0 = r0a[0] + r0a[1], q0 = r0a[0] - r0a[1];
        float r0 = r1a[0] + r1a[1], s0 = r1a[0] - r1a[1];
        ll_a[0] = (p0 + r0) * 0.5f; hl_a[0] = (p0 - r0) * 0.5f;
        lh_a[0] = (q0 + s0) * 0.5f; hh_a[0] = (q0 - s0) * 0.5f;
        float p1 = r0a[2] + r0a[3], q1 = r0a[2] - r0a[3];
        float r1 = r1a[2] + r1a[3], s1 = r1a[2] - r1a[3];
        ll_a[1] = (p1 + r1) * 0.5f; hl_a[1] = (p1 - r1) * 0.5f;
        lh_a[1] = (q1 + s1) * 0.5f; hh_a[1] = (q1 - s1) * 0.5f;
    }
    {
        float p0 = r0b[0] + r0b[1], q0 = r0b[0] - r0b[1];
        float r0 = r1b[0] + r1b[1], s0 = r1b[0] - r1b[1];
        ll_b[0] = (p0 + r0) * 0.5f; hl_b[0] = (p0 - r0) * 0.5f;
        lh_b[0] = (q0 + s0) * 0.5f; hh_b[0] = (q0 - s0) * 0.5f;
        float p1 = r0b[2] + r0b[3], q1 = r0b[2] - r0b[3];
        float r1 = r1b[2] + r1b[3], s1 = r1b[2] - r1b[3];
        ll_b[1] = (p1 + r1) * 0.5f; hl_b[1] = (p1 - r1) * 0.5f;
        lh_b[1] = (q1 + s1) * 0.5f; hh_b[1] = (q1 - s1) * 0.5f;
    }

    *reinterpret_cast<f32x2*>(&lds[w][0][2 * lane])       = ll_a;
    *reinterpret_cast<f32x2*>(&lds[w][0][128 + 2 * lane]) = ll_b;
    *reinterpret_cast<f32x2*>(&lds[w][1][2 * lane])       = lh_a;
    *reinterpret_cast<f32x2*>(&lds[w][1][128 + 2 * lane]) = lh_b;
    *reinterpret_cast<f32x2*>(&lds[w][2][2 * lane])       = hl_a;
    *reinterpret_cast<f32x2*>(&lds[w][2][128 + 2 * lane]) = hl_b;
    *reinterpret_cast<f32x2*>(&lds[w][3][2 * lane])       = hh_a;
    *reinterpret_cast<f32x2*>(&lds[w][3][128 + 2 * lane]) = hh_b;

    __syncthreads();

    // ---- Phase B: wave w writes plane w, 4KB contiguous, rotated rows ----
    float* plane_base = out + (size_t)w * NPLANE + (size_t)bc * (HO * WO)
                            + (size_t)(h4 * 4) * WO + 4 * lane;
#pragma unroll
    for (int s = 0; s < 4; ++s) {
        const int r = (w + s) & 3;
        const f32x4 v = *reinterpret_cast<const f32x4*>(&lds[r][w][4 * lane]);
        *reinterpret_cast<f32x4*>(plane_base + (size_t)r * WO) = v;
    }
}

extern "C" void kernel_launch(void* const* d_in, const int* in_sizes, int n_in,
                              void* d_out, int out_size, void* d_ws, size_t ws_size,
                              hipStream_t stream) {
    const float* x = (const float*)d_in[0];
    float* out = (float*)d_out;
    haar_kernel<<<65536, 256, 0, stream>>>(x, out);
}